// Round 1
// baseline (8342.065 us; speedup 1.0000x reference)
//
#include <hip/hip_runtime.h>

typedef unsigned short u16;
typedef unsigned int u32;
typedef __attribute__((ext_vector_type(4))) float f32x4;
typedef __attribute__((ext_vector_type(8))) __bf16 bf16x8;

#define TSTEPS 50
#define BB 256
#define II 1024
#define HH 4096
#define LL 10

__device__ __forceinline__ u16 f2bf(float f){
  u32 u = __float_as_uint(f);
  u += 0x7fffu + ((u >> 16) & 1u);
  return (u16)(u >> 16);
}
__device__ __forceinline__ float bf2f(u16 u){ return __uint_as_float(((u32)u) << 16); }

__device__ __forceinline__ void async_cp16(const void* g, void* l){
  auto gp = (const __attribute__((address_space(1))) void*)(unsigned long long)(g);
  auto lp = (__attribute__((address_space(3))) void*)(unsigned int)(unsigned long long)(l);
  __builtin_amdgcn_global_load_lds(gp, lp, 16, 0, 0);
}

// C[M,N] (+)= sum_k A1[m,k]*B1[n,k] + sum_k A2[m,k]*B2[n,k]   (bf16 in, f32 acc)
// MODE 0: C = acc (fresh write). MODE 1: C += acc (f32 RMW) and Cb = bf16(C).
template<int BM,int BN,int WM,int WN,int MODE>
__global__ void __launch_bounds__(256) gemm2(
    const u16* __restrict__ A1, int lda1,
    const u16* __restrict__ B1, int ldb1, int K1len,
    const u16* __restrict__ A2, int lda2,
    const u16* __restrict__ B2, int ldb2, int K2len,
    float* __restrict__ C, u16* __restrict__ Cb, int ldc)
{
  constexpr int FM = WM/16, FN = WN/16;
  constexpr int WGM = BM/WM;
  __shared__ u16 lsA[BM*64];
  __shared__ u16 lsB[BN*64];
  const int tid = threadIdx.x;
  const int lane = tid & 63;
  const int wid = tid >> 6;
  const int wm = wid % WGM;
  const int wn = wid / WGM;
  const int m0 = blockIdx.y * BM;
  const int n0 = blockIdx.x * BN;

  f32x4 acc[FM][FN];
#pragma unroll
  for (int a=0;a<FM;++a)
#pragma unroll
    for (int b=0;b<FN;++b) acc[a][b] = f32x4{0.f,0.f,0.f,0.f};

  const u16* As[2] = {A1, A2};
  const u16* Bs[2] = {B1, B2};
  const int ldas[2] = {lda1, lda2};
  const int ldbs[2] = {ldb1, ldb2};
  const int Ks[2]   = {K1len, K2len};

#pragma unroll
  for (int p = 0; p < 2; ++p) {
    const u16* __restrict__ A  = As[p];
    const u16* __restrict__ Bm = Bs[p];
    const int lda = ldas[p], ldb = ldbs[p], K = Ks[p];
    for (int k0 = 0; k0 < K; k0 += 64) {
      // stage A tile [BM][64] bf16, XOR-swizzled via pre-swizzled global source
#pragma unroll
      for (int c = 0; c < (BM*128/1024)/4; ++c) {
        int q = c*4 + wid;
        int o = q*1024 + lane*16;
        int row = o >> 7;
        int cb = (o & 127) ^ ((row & 7) << 4);
        async_cp16(A + (size_t)(m0 + row)*lda + k0 + (cb >> 1), (char*)lsA + q*1024);
      }
#pragma unroll
      for (int c = 0; c < (BN*128/1024)/4; ++c) {
        int q = c*4 + wid;
        int o = q*1024 + lane*16;
        int row = o >> 7;
        int cb = (o & 127) ^ ((row & 7) << 4);
        async_cp16(Bm + (size_t)(n0 + row)*ldb + k0 + (cb >> 1), (char*)lsB + q*1024);
      }
      __syncthreads();
#pragma unroll
      for (int kk = 0; kk < 2; ++kk) {
        bf16x8 af[FM], bfr[FN];
#pragma unroll
        for (int fm=0; fm<FM; ++fm) {
          int r = wm*WM + fm*16 + (lane & 15);
          int kb = kk*64 + ((lane >> 4) << 4);
          af[fm] = *(const bf16x8*)((const char*)lsA + r*128 + (kb ^ ((r & 7) << 4)));
        }
#pragma unroll
        for (int fn=0; fn<FN; ++fn) {
          int r = wn*WN + fn*16 + (lane & 15);
          int kb = kk*64 + ((lane >> 4) << 4);
          bfr[fn] = *(const bf16x8*)((const char*)lsB + r*128 + (kb ^ ((r & 7) << 4)));
        }
#pragma unroll
        for (int fm=0; fm<FM; ++fm)
#pragma unroll
          for (int fn=0; fn<FN; ++fn)
            acc[fm][fn] = __builtin_amdgcn_mfma_f32_16x16x32_bf16(af[fm], bfr[fn], acc[fm][fn], 0, 0, 0);
      }
      __syncthreads();
    }
  }

#pragma unroll
  for (int fm=0; fm<FM; ++fm)
#pragma unroll
    for (int fn=0; fn<FN; ++fn)
#pragma unroll
      for (int r=0; r<4; ++r) {
        int row = m0 + wm*WM + fm*16 + ((lane >> 4) << 2) + r;
        int col = n0 + wn*WN + fn*16 + (lane & 15);
        size_t idx = (size_t)row*ldc + col;
        float val = acc[fm][fn][r];
        if constexpr (MODE == 0) {
          C[idx] = val;
        } else {
          float nw = C[idx] + val;
          C[idx] = nw;
          Cb[idx] = f2bf(nw);
        }
      }
}

// transpose-dump a 64x64 tile of per-thread values (compute mapping: flat=e*256+tid,
// inner=flat&63 (fast dim), outer=flat>>6) into out[(h0+inner)*BB + b0+outer]
__device__ __forceinline__ void tdump(u16* ls, const u16 (&vals)[16], u16* __restrict__ out,
                                      int h0, int b0, int tid){
  __syncthreads();
#pragma unroll
  for (int e=0;e<16;++e){ int f=e*256+tid; ls[(f & 63)*66 + (f >> 6)] = vals[e]; }
  __syncthreads();
#pragma unroll
  for (int e=0;e<16;++e){
    int f=e*256+tid; int bl=f & 63, hl=f >> 6;
    out[(size_t)(h0+hl)*BB + b0 + bl] = ls[hl*66 + bl];
  }
}

__global__ void __launch_bounds__(256) step_state(
    const float* __restrict__ incur,
    float* __restrict__ v, float* __restrict__ iS, float* __restrict__ sc,
    float* __restrict__ tqi, float* __restrict__ tpr, float* __restrict__ tqr,
    const u16* __restrict__ zb_old,
    u16* __restrict__ zb_new, u16* __restrict__ zT_new,
    u16* __restrict__ tqiT, u16* __restrict__ tprT, u16* __restrict__ tqrT)
{
  __shared__ u16 ls[64*66];
  const int tid = threadIdx.x;
  const int h0 = blockIdx.x * 64;
  const int b0 = blockIdx.y * 64;
  u16 vz[16], vq[16], vp[16], vr[16];
#pragma unroll
  for (int e=0;e<16;++e){
    int f = e*256 + tid;
    int hl = f & 63, bl = f >> 6;
    size_t idx = (size_t)(b0+bl)*HH + h0 + hl;
    float ic = incur[idx];
    float vv = v[idx], ii = iS[idx];
    float vdec = vv + 0.05f*((0.0f - vv) + ii);
    float idec = ii - 0.1f*ii;
    float z = (vdec >= 0.5f) ? 1.0f : 0.0f;
    v[idx] = (vdec >= 0.5f) ? 0.0f : vdec;
    iS[idx] = idec + ic;
    float zold = bf2f(zb_old[idx]);
    float q = tqi[idx]; q += 0.0005f*(0.001f*z - q);    tqi[idx] = q;
    float pp = tpr[idx]; pp += 0.0005f*(0.001f*zold - pp); tpr[idx] = pp;
    float rr = tqr[idx]; rr += 0.0005f*(0.001f*z - rr); tqr[idx] = rr;
    sc[idx] += z;
    u16 zb16 = f2bf(z);
    zb_new[idx] = zb16;
    vz[e] = zb16;
    vq[e] = f2bf(-1e-4f * q);   // fold -ETA_MINUS
    vp[e] = f2bf(0.01f * pp);   // fold +ETA_PLUS
    vr[e] = f2bf(-1e-4f * rr);  // fold -ETA_MINUS
  }
  tdump(ls, vz, zT_new, h0, b0, tid);
  tdump(ls, vq, tqiT,  h0, b0, tid);
  tdump(ls, vp, tprT,  h0, b0, tid);
  tdump(ls, vr, tqrT,  h0, b0, tid);
}

__global__ void __launch_bounds__(256) step_tpi(
    const u16* __restrict__ xbt, float* __restrict__ tpi,
    u16* __restrict__ tpiT, u16* __restrict__ xbT)
{
  __shared__ u16 ls[64*66];
  const int tid = threadIdx.x;
  const int i0 = blockIdx.x * 64;
  const int b0 = blockIdx.y * 64;
  u16 vp[16], vx[16];
#pragma unroll
  for (int e=0;e<16;++e){
    int f = e*256 + tid;
    int il = f & 63, bl = f >> 6;
    size_t idx = (size_t)(b0+bl)*II + i0 + il;
    u16 xu = xbt[idx];
    float pre = bf2f(xu);
    float p = tpi[idx]; p += 0.0005f*(0.001f*pre - p); tpi[idx] = p;
    vp[e] = f2bf(0.01f*p);  // fold +ETA_PLUS
    vx[e] = xu;
  }
  tdump(ls, vp, tpiT, i0, b0, tid);
  tdump(ls, vx, xbT,  i0, b0, tid);
}

__global__ void __launch_bounds__(256) cast_x(const float* __restrict__ x, u16* __restrict__ xb, long long n){
  long long i = (long long)blockIdx.x*blockDim.x + threadIdx.x;
  long long stride = (long long)gridDim.x*blockDim.x;
  for (; i < n; i += stride) xb[i] = f2bf(x[i]);
}

__global__ void __launch_bounds__(256) cast_w(const float* __restrict__ w0, float* __restrict__ wf,
                                              u16* __restrict__ wb, long long n){
  long long i = (long long)blockIdx.x*blockDim.x + threadIdx.x;
  long long stride = (long long)gridDim.x*blockDim.x;
  for (; i < n; i += stride){ float vv = w0[i]; wf[i] = vv; wb[i] = f2bf(vv); }
}

__global__ void __launch_bounds__(256) fin_logits(const float* __restrict__ sc,
                                                  float* __restrict__ logits, float* __restrict__ total){
  __shared__ float bins[LL];
  const int tid = threadIdx.x;
  const int b = blockIdx.x;
  if (tid < LL) bins[tid] = 0.f;
  __syncthreads();
#pragma unroll
  for (int e=0;e<16;++e){
    int h = e*256 + tid;
    float vv = sc[(size_t)b*HH + h];
    int a = h/409; if (a > 9) a = 9;
    atomicAdd(&bins[a], vv);
  }
  __syncthreads();
  if (tid < LL){
    float cnt = (tid==9) ? 415.f : 409.f;
    logits[b*LL + tid] = bins[tid] / (50.f * cnt);
  }
  if (tid == 0){
    float s = 0.f;
    for (int l=0;l<LL;++l) s += bins[l];
    atomicAdd(total, s);
  }
}

__global__ void __launch_bounds__(256) fin_spikecnt(const float* __restrict__ sc,
                                                    const int* __restrict__ label, float* __restrict__ out){
  int h = blockIdx.x*256 + threadIdx.x;
  for (int b=0;b<BB;++b){
    int l = label[b];
    out[(size_t)l*HH + h] += sc[(size_t)b*HH + h];
  }
}

__global__ void __launch_bounds__(256) fin_labelcnt(const int* __restrict__ label, float* __restrict__ out){
  __shared__ int bins[LL];
  const int tid = threadIdx.x;
  if (tid < LL) bins[tid] = 0;
  __syncthreads();
  atomicAdd(&bins[label[tid]], 1);
  __syncthreads();
  if (tid < LL) out[tid] = 50.f * (float)bins[tid];
}

extern "C" void kernel_launch(void* const* d_in, const int* in_sizes, int n_in,
                              void* d_out, int out_size, void* d_ws, size_t ws_size,
                              hipStream_t stream)
{
  (void)in_sizes; (void)n_in; (void)out_size; (void)ws_size;
  const float* x      = (const float*)d_in[0];
  const int*   label  = (const int*)d_in[1];
  const float* w_in0  = (const float*)d_in[2];
  const float* w_rec0 = (const float*)d_in[3];

  float* out      = (float*)d_out;
  float* o_logits = out;                            // 2560
  float* o_total  = out + 2560;                     // 1
  float* o_win    = out + 2561;                     // H*I f32 master (lives in d_out)
  float* o_wrec   = o_win + (size_t)HH*II;          // H*H
  float* o_sc     = o_wrec + (size_t)HH*HH;         // L*H
  float* o_lc     = o_sc + (size_t)LL*HH;           // L

  char* cur = (char*)d_ws;
  auto alloc = [&](size_t bytes)->char*{ char* p = cur; cur += (bytes + 255) & ~(size_t)255; return p; };
  u16*   xb   = (u16*)  alloc((size_t)TSTEPS*BB*II*2);
  u16*   wib  = (u16*)  alloc((size_t)HH*II*2);
  u16*   wrb  = (u16*)  alloc((size_t)HH*HH*2);
  float* v    = (float*)alloc((size_t)BB*HH*4);
  float* iS   = (float*)alloc((size_t)BB*HH*4);
  float* sc   = (float*)alloc((size_t)BB*HH*4);
  float* tpi  = (float*)alloc((size_t)BB*II*4);
  float* tqi  = (float*)alloc((size_t)BB*HH*4);
  float* tpr  = (float*)alloc((size_t)BB*HH*4);
  float* tqr  = (float*)alloc((size_t)BB*HH*4);
  float* incur= (float*)alloc((size_t)BB*HH*4);
  u16*   zb0  = (u16*)  alloc((size_t)BB*HH*2);
  u16*   zb1  = (u16*)  alloc((size_t)BB*HH*2);
  u16*   zT0  = (u16*)  alloc((size_t)HH*BB*2);
  u16*   zT1  = (u16*)  alloc((size_t)HH*BB*2);
  u16*   tpiT = (u16*)  alloc((size_t)II*BB*2);
  u16*   xbT  = (u16*)  alloc((size_t)II*BB*2);
  u16*   tqiT = (u16*)  alloc((size_t)HH*BB*2);
  u16*   tprT = (u16*)  alloc((size_t)HH*BB*2);
  u16*   tqrT = (u16*)  alloc((size_t)HH*BB*2);
  u16* zb[2] = {zb0, zb1};
  u16* zT[2] = {zT0, zT1};

  hipMemsetAsync(v,    0, (size_t)BB*HH*4, stream);
  hipMemsetAsync(iS,   0, (size_t)BB*HH*4, stream);
  hipMemsetAsync(sc,   0, (size_t)BB*HH*4, stream);
  hipMemsetAsync(tpi,  0, (size_t)BB*II*4, stream);
  hipMemsetAsync(tqi,  0, (size_t)BB*HH*4, stream);
  hipMemsetAsync(tpr,  0, (size_t)BB*HH*4, stream);
  hipMemsetAsync(tqr,  0, (size_t)BB*HH*4, stream);
  hipMemsetAsync(zb0,  0, (size_t)BB*HH*2, stream);
  hipMemsetAsync(zb1,  0, (size_t)BB*HH*2, stream);
  hipMemsetAsync(zT0,  0, (size_t)HH*BB*2, stream);
  hipMemsetAsync(zT1,  0, (size_t)HH*BB*2, stream);
  hipMemsetAsync(o_total, 0, 4, stream);
  hipMemsetAsync(o_sc, 0, (size_t)LL*HH*4, stream);

  cast_w<<<1024, 256, 0, stream>>>(w_in0,  o_win,  wib, (long long)HH*II);
  cast_w<<<2048, 256, 0, stream>>>(w_rec0, o_wrec, wrb, (long long)HH*HH);
  cast_x<<<2048, 256, 0, stream>>>(x, xb, (long long)TSTEPS*BB*II);

  for (int t = 0; t < TSTEPS; ++t){
    int wi = t & 1, ri = wi ^ 1;
    const u16* xbt = xb + (size_t)t*BB*II;

    // in_cur = pre @ w_in^T + z_old @ w_rec^T
    gemm2<64,64,32,32,0><<<dim3(HH/64, BB/64), 256, 0, stream>>>(
        xbt, II, wib, II, II,
        zb[ri], HH, wrb, HH, HH,
        incur, (u16*)nullptr, HH);

    step_state<<<dim3(HH/64, BB/64), 256, 0, stream>>>(
        incur, v, iS, sc, tqi, tpr, tqr,
        zb[ri], zb[wi], zT[wi], tqiT, tprT, tqrT);

    step_tpi<<<dim3(II/64, BB/64), 256, 0, stream>>>(xbt, tpi, tpiT, xbT);

    // w_in += 0.01 * z_new^T tp_i - 1e-4 * tq_i^T pre   (coeffs folded into bf16 operands)
    gemm2<128,128,64,64,1><<<dim3(II/128, HH/128), 256, 0, stream>>>(
        zT[wi], BB, tpiT, BB, BB,
        tqiT,  BB, xbT,  BB, BB,
        o_win, wib, II);

    // w_rec += 0.01 * z_new^T tp_r - 1e-4 * tq_r^T z_old
    gemm2<128,128,64,64,1><<<dim3(HH/128, HH/128), 256, 0, stream>>>(
        zT[wi], BB, tprT, BB, BB,
        tqrT,  BB, zT[ri], BB, BB,
        o_wrec, wrb, HH);
  }

  fin_logits  <<<BB, 256, 0, stream>>>(sc, o_logits, o_total);
  fin_spikecnt<<<HH/256, 256, 0, stream>>>(sc, label, o_sc);
  fin_labelcnt<<<1, 256, 0, stream>>>(label, o_lc);
}

// Round 2
// 6139.203 us; speedup vs baseline: 1.3588x; 1.3588x over previous
//
#include <hip/hip_runtime.h>

typedef unsigned short u16;
typedef unsigned int u32;
typedef __attribute__((ext_vector_type(4))) float f32x4;
typedef __attribute__((ext_vector_type(4))) u16 u16x4;
typedef __attribute__((ext_vector_type(8))) __bf16 bf16x8;

#define TSTEPS 50
#define BB 256
#define II 1024
#define HH 4096
#define LL 10
#define NPLANE ((size_t)BB*HH)

__device__ __forceinline__ u16 f2bf(float f){
  u32 u = __float_as_uint(f);
  u += 0x7fffu + ((u >> 16) & 1u);
  return (u16)(u >> 16);
}
__device__ __forceinline__ float bf2f(u16 u){ return __uint_as_float(((u32)u) << 16); }

__device__ __forceinline__ void async_cp16(const void* g, void* l){
  auto gp = (const __attribute__((address_space(1))) void*)(unsigned long long)(g);
  auto lp = (__attribute__((address_space(3))) void*)(unsigned int)(unsigned long long)(l);
  __builtin_amdgcn_global_load_lds(gp, lp, 16, 0, 0);
}

// ---------------- forward: split-K over 5 planes of K=1024 -----------------
// plane 0: x_t @ w_in^T ; planes 1..4: z_old @ w_rec^T (k-chunks of 1024)
// C tile: 64(batch) x 64(H), 4 waves of 32x32. Writes f32 partial plane.
__global__ void __launch_bounds__(256) gemm_fwd(
    const u16* __restrict__ xbt, const u16* __restrict__ wib,
    const u16* __restrict__ zb,  const u16* __restrict__ wrb,
    float* __restrict__ pbuf)
{
  constexpr int BM=64, BN=64;
  __shared__ u16 lsA[BM*64];
  __shared__ u16 lsB[BN*64];
  const int tid = threadIdx.x;
  const int lane = tid & 63;
  const int wid = tid >> 6;
  const int wm = wid & 1;          // 2 wave-rows (m)
  const int wn = wid >> 1;         // 2 wave-cols (n)
  const int m0 = blockIdx.y * BM;  // batch
  const int n0 = blockIdx.x * BN;  // H
  const int z  = blockIdx.z;

  const u16* __restrict__ A;  const u16* __restrict__ Bm;
  int lda, ldb;
  if (z == 0){ A = xbt; lda = II; Bm = wib; ldb = II; }
  else { A = zb + (z-1)*1024; lda = HH; Bm = wrb + (z-1)*1024; ldb = HH; }
  float* __restrict__ C = pbuf + (size_t)z*NPLANE;

  f32x4 acc[2][2];
#pragma unroll
  for (int a=0;a<2;++a)
#pragma unroll
    for (int b=0;b<2;++b) acc[a][b] = f32x4{0.f,0.f,0.f,0.f};

  for (int k0 = 0; k0 < 1024; k0 += 64) {
#pragma unroll
    for (int c = 0; c < 2; ++c) {
      int q = c*4 + wid;
      int o = q*1024 + lane*16;
      int row = o >> 7;
      int cb = (o & 127) ^ ((row & 7) << 4);
      async_cp16(A + (size_t)(m0 + row)*lda + k0 + (cb >> 1), (char*)lsA + q*1024);
    }
#pragma unroll
    for (int c = 0; c < 2; ++c) {
      int q = c*4 + wid;
      int o = q*1024 + lane*16;
      int row = o >> 7;
      int cb = (o & 127) ^ ((row & 7) << 4);
      async_cp16(Bm + (size_t)(n0 + row)*ldb + k0 + (cb >> 1), (char*)lsB + q*1024);
    }
    __syncthreads();
#pragma unroll
    for (int kk = 0; kk < 2; ++kk) {
      bf16x8 af[2], bfr[2];
#pragma unroll
      for (int fm=0; fm<2; ++fm) {
        int r = wm*32 + fm*16 + (lane & 15);
        int kb = kk*64 + ((lane >> 4) << 4);
        af[fm] = *(const bf16x8*)((const char*)lsA + r*128 + (kb ^ ((r & 7) << 4)));
      }
#pragma unroll
      for (int fn=0; fn<2; ++fn) {
        int r = wn*32 + fn*16 + (lane & 15);
        int kb = kk*64 + ((lane >> 4) << 4);
        bfr[fn] = *(const bf16x8*)((const char*)lsB + r*128 + (kb ^ ((r & 7) << 4)));
      }
#pragma unroll
      for (int fm=0; fm<2; ++fm)
#pragma unroll
        for (int fn=0; fn<2; ++fn)
          acc[fm][fn] = __builtin_amdgcn_mfma_f32_16x16x32_bf16(af[fm], bfr[fn], acc[fm][fn], 0, 0, 0);
    }
    __syncthreads();
  }

#pragma unroll
  for (int fm=0; fm<2; ++fm)
#pragma unroll
    for (int fn=0; fn<2; ++fn)
#pragma unroll
      for (int r=0; r<4; ++r) {
        int row = m0 + wm*32 + fm*16 + ((lane >> 4) << 2) + r;
        int col = n0 + wn*32 + fn*16 + (lane & 15);
        C[(size_t)row*HH + col] = acc[fm][fn][r];
      }
}

// ---------------- weight-update GEMM (2 products, f32 RMW + bf16 shadow) ----
template<int BM,int BN,int WM,int WN>
__global__ void __launch_bounds__(256) gemm_upd(
    const u16* __restrict__ A1, const u16* __restrict__ B1,
    const u16* __restrict__ A2, const u16* __restrict__ B2,
    float* __restrict__ C, u16* __restrict__ Cb, int ldc)
{
  constexpr int FM = WM/16, FN = WN/16;
  constexpr int WGM = BM/WM;
  __shared__ u16 lsA[BM*64];
  __shared__ u16 lsB[BN*64];
  const int tid = threadIdx.x;
  const int lane = tid & 63;
  const int wid = tid >> 6;
  const int wm = wid % WGM;
  const int wn = wid / WGM;
  const int m0 = blockIdx.y * BM;
  const int n0 = blockIdx.x * BN;

  f32x4 acc[FM][FN];
#pragma unroll
  for (int a=0;a<FM;++a)
#pragma unroll
    for (int b=0;b<FN;++b) acc[a][b] = f32x4{0.f,0.f,0.f,0.f};

  const u16* As[2] = {A1, A2};
  const u16* Bs[2] = {B1, B2};

#pragma unroll
  for (int p = 0; p < 2; ++p) {
    const u16* __restrict__ A  = As[p];
    const u16* __restrict__ Bm = Bs[p];
    for (int k0 = 0; k0 < BB; k0 += 64) {
#pragma unroll
      for (int c = 0; c < (BM*128/1024)/4; ++c) {
        int q = c*4 + wid;
        int o = q*1024 + lane*16;
        int row = o >> 7;
        int cb = (o & 127) ^ ((row & 7) << 4);
        async_cp16(A + (size_t)(m0 + row)*BB + k0 + (cb >> 1), (char*)lsA + q*1024);
      }
#pragma unroll
      for (int c = 0; c < (BN*128/1024)/4; ++c) {
        int q = c*4 + wid;
        int o = q*1024 + lane*16;
        int row = o >> 7;
        int cb = (o & 127) ^ ((row & 7) << 4);
        async_cp16(Bm + (size_t)(n0 + row)*BB + k0 + (cb >> 1), (char*)lsB + q*1024);
      }
      __syncthreads();
#pragma unroll
      for (int kk = 0; kk < 2; ++kk) {
        bf16x8 af[FM], bfr[FN];
#pragma unroll
        for (int fm=0; fm<FM; ++fm) {
          int r = wm*WM + fm*16 + (lane & 15);
          int kb = kk*64 + ((lane >> 4) << 4);
          af[fm] = *(const bf16x8*)((const char*)lsA + r*128 + (kb ^ ((r & 7) << 4)));
        }
#pragma unroll
        for (int fn=0; fn<FN; ++fn) {
          int r = wn*WN + fn*16 + (lane & 15);
          int kb = kk*64 + ((lane >> 4) << 4);
          bfr[fn] = *(const bf16x8*)((const char*)lsB + r*128 + (kb ^ ((r & 7) << 4)));
        }
#pragma unroll
        for (int fm=0; fm<FM; ++fm)
#pragma unroll
          for (int fn=0; fn<FN; ++fn)
            acc[fm][fn] = __builtin_amdgcn_mfma_f32_16x16x32_bf16(af[fm], bfr[fn], acc[fm][fn], 0, 0, 0);
      }
      __syncthreads();
    }
  }

#pragma unroll
  for (int fm=0; fm<FM; ++fm)
#pragma unroll
    for (int fn=0; fn<FN; ++fn)
#pragma unroll
      for (int r=0; r<4; ++r) {
        int row = m0 + wm*WM + fm*16 + ((lane >> 4) << 2) + r;
        int col = n0 + wn*WN + fn*16 + (lane & 15);
        size_t idx = (size_t)row*ldc + col;
        float nw = C[idx] + acc[fm][fn][r];
        C[idx] = nw;
        Cb[idx] = f2bf(nw);
      }
}

// ---------------- per-step elementwise + transposes -------------------------
// tile: 64 h x 16 b, grid (HH/64, BB/16) = 1024 blocks
__global__ void __launch_bounds__(256) step_state(
    const float* __restrict__ pbuf,
    float* __restrict__ v, float* __restrict__ iS, float* __restrict__ sc,
    float* __restrict__ tqi, float* __restrict__ tpr, float* __restrict__ tqr,
    const u16* __restrict__ zb_old,
    u16* __restrict__ zb_new, u16* __restrict__ zT_new,
    u16* __restrict__ tqiT, u16* __restrict__ tprT, u16* __restrict__ tqrT)
{
  __shared__ u16 ls[4][64*17];
  const int tid = threadIdx.x;
  const int h0 = blockIdx.x * 64;
  const int b0 = blockIdx.y * 16;
  u16 vz[4], vq[4], vp[4], vr[4];
#pragma unroll
  for (int e=0;e<4;++e){
    int f = e*256 + tid;
    int hl = f & 63, bl = f >> 6;
    size_t idx = (size_t)(b0+bl)*HH + h0 + hl;
    float ic = pbuf[idx] + pbuf[idx + NPLANE] + pbuf[idx + 2*NPLANE]
             + pbuf[idx + 3*NPLANE] + pbuf[idx + 4*NPLANE];
    float vv = v[idx], ii = iS[idx];
    float vdec = vv + 0.05f*((0.0f - vv) + ii);
    float idec = ii - 0.1f*ii;
    float z = (vdec >= 0.5f) ? 1.0f : 0.0f;
    v[idx] = (vdec >= 0.5f) ? 0.0f : vdec;
    iS[idx] = idec + ic;
    float zold = bf2f(zb_old[idx]);
    float q = tqi[idx]; q += 0.0005f*(0.001f*z - q);    tqi[idx] = q;
    float pp = tpr[idx]; pp += 0.0005f*(0.001f*zold - pp); tpr[idx] = pp;
    float rr = tqr[idx]; rr += 0.0005f*(0.001f*z - rr); tqr[idx] = rr;
    sc[idx] += z;
    u16 zb16 = f2bf(z);
    zb_new[idx] = zb16;
    vz[e] = zb16;
    vq[e] = f2bf(-1e-4f * q);   // fold -ETA_MINUS
    vp[e] = f2bf(0.01f * pp);   // fold +ETA_PLUS
    vr[e] = f2bf(-1e-4f * rr);  // fold -ETA_MINUS
  }
#pragma unroll
  for (int e=0;e<4;++e){
    int f=e*256+tid; int hl=f&63, bl=f>>6; int o = hl*17+bl;
    ls[0][o]=vz[e]; ls[1][o]=vq[e]; ls[2][o]=vp[e]; ls[3][o]=vr[e];
  }
  __syncthreads();
#pragma unroll
  for (int e=0;e<4;++e){
    int f=e*256+tid; int bl=f&15, hl=f>>4; int o=hl*17+bl;
    size_t oi = (size_t)(h0+hl)*BB + b0 + bl;
    zT_new[oi]=ls[0][o]; tqiT[oi]=ls[1][o]; tprT[oi]=ls[2][o]; tqrT[oi]=ls[3][o];
  }
}

// tile: 64 i x 16 b, grid (II/64, BB/16) = 256 blocks
__global__ void __launch_bounds__(256) step_tpi(
    const u16* __restrict__ xbt, float* __restrict__ tpi,
    u16* __restrict__ tpiT, u16* __restrict__ xbT)
{
  __shared__ u16 ls[2][64*17];
  const int tid = threadIdx.x;
  const int i0 = blockIdx.x * 64;
  const int b0 = blockIdx.y * 16;
  u16 vp[4], vx[4];
#pragma unroll
  for (int e=0;e<4;++e){
    int f = e*256 + tid;
    int il = f & 63, bl = f >> 6;
    size_t idx = (size_t)(b0+bl)*II + i0 + il;
    u16 xu = xbt[idx];
    float pre = bf2f(xu);
    float p = tpi[idx]; p += 0.0005f*(0.001f*pre - p); tpi[idx] = p;
    vp[e] = f2bf(0.01f*p);  // fold +ETA_PLUS
    vx[e] = xu;
  }
#pragma unroll
  for (int e=0;e<4;++e){
    int f=e*256+tid; int il=f&63, bl=f>>6; int o = il*17+bl;
    ls[0][o]=vp[e]; ls[1][o]=vx[e];
  }
  __syncthreads();
#pragma unroll
  for (int e=0;e<4;++e){
    int f=e*256+tid; int bl=f&15, il=f>>4; int o=il*17+bl;
    size_t oi = (size_t)(i0+il)*BB + b0 + bl;
    tpiT[oi]=ls[0][o]; xbT[oi]=ls[1][o];
  }
}

// ---------------- casts and finalize ---------------------------------------
__global__ void __launch_bounds__(256) cast_x(const f32x4* __restrict__ x, u16x4* __restrict__ xb, long long n4){
  long long i = (long long)blockIdx.x*blockDim.x + threadIdx.x;
  long long stride = (long long)gridDim.x*blockDim.x;
  for (; i < n4; i += stride){
    f32x4 vv = x[i];
    u16x4 o;
#pragma unroll
    for (int j=0;j<4;++j) o[j] = f2bf(vv[j]);
    xb[i] = o;
  }
}

__global__ void __launch_bounds__(256) cast_w(const f32x4* __restrict__ w0, f32x4* __restrict__ wf,
                                              u16x4* __restrict__ wb, long long n4){
  long long i = (long long)blockIdx.x*blockDim.x + threadIdx.x;
  long long stride = (long long)gridDim.x*blockDim.x;
  for (; i < n4; i += stride){
    f32x4 vv = w0[i];
    wf[i] = vv;
    u16x4 o;
#pragma unroll
    for (int j=0;j<4;++j) o[j] = f2bf(vv[j]);
    wb[i] = o;
  }
}

__global__ void __launch_bounds__(256) fin_logits(const float* __restrict__ sc,
                                                  float* __restrict__ logits, float* __restrict__ total){
  __shared__ float bins[LL];
  const int tid = threadIdx.x;
  const int b = blockIdx.x;
  if (tid < LL) bins[tid] = 0.f;
  __syncthreads();
#pragma unroll
  for (int e=0;e<16;++e){
    int h = e*256 + tid;
    float vv = sc[(size_t)b*HH + h];
    int a = h/409; if (a > 9) a = 9;
    atomicAdd(&bins[a], vv);
  }
  __syncthreads();
  if (tid < LL){
    float cnt = (tid==9) ? 415.f : 409.f;
    logits[b*LL + tid] = bins[tid] / (50.f * cnt);
  }
  if (tid == 0){
    float s = 0.f;
    for (int l=0;l<LL;++l) s += bins[l];
    atomicAdd(total, s);
  }
}

__global__ void __launch_bounds__(256) fin_spikecnt(const float* __restrict__ sc,
                                                    const int* __restrict__ label, float* __restrict__ out){
  int h = blockIdx.x*256 + threadIdx.x;
  for (int b=0;b<BB;++b){
    int l = label[b];
    out[(size_t)l*HH + h] += sc[(size_t)b*HH + h];
  }
}

__global__ void __launch_bounds__(256) fin_labelcnt(const int* __restrict__ label, float* __restrict__ out){
  __shared__ int bins[LL];
  const int tid = threadIdx.x;
  if (tid < LL) bins[tid] = 0;
  __syncthreads();
  atomicAdd(&bins[label[tid]], 1);
  __syncthreads();
  if (tid < LL) out[tid] = 50.f * (float)bins[tid];
}

extern "C" void kernel_launch(void* const* d_in, const int* in_sizes, int n_in,
                              void* d_out, int out_size, void* d_ws, size_t ws_size,
                              hipStream_t stream)
{
  (void)in_sizes; (void)n_in; (void)out_size; (void)ws_size;
  const float* x      = (const float*)d_in[0];
  const int*   label  = (const int*)d_in[1];
  const float* w_in0  = (const float*)d_in[2];
  const float* w_rec0 = (const float*)d_in[3];

  float* out      = (float*)d_out;
  float* o_logits = out;                            // 2560
  float* o_total  = out + 2560;                     // 1
  float* o_win    = out + 2561;                     // H*I f32 master (lives in d_out)
  float* o_wrec   = o_win + (size_t)HH*II;          // H*H
  float* o_sc     = o_wrec + (size_t)HH*HH;         // L*H
  float* o_lc     = o_sc + (size_t)LL*HH;           // L

  char* cur = (char*)d_ws;
  auto alloc = [&](size_t bytes)->char*{ char* p = cur; cur += (bytes + 255) & ~(size_t)255; return p; };
  u16*   xb   = (u16*)  alloc((size_t)TSTEPS*BB*II*2);
  u16*   wib  = (u16*)  alloc((size_t)HH*II*2);
  u16*   wrb  = (u16*)  alloc((size_t)HH*HH*2);
  float* v    = (float*)alloc((size_t)BB*HH*4);
  float* iS   = (float*)alloc((size_t)BB*HH*4);
  float* sc   = (float*)alloc((size_t)BB*HH*4);
  float* tpi  = (float*)alloc((size_t)BB*II*4);
  float* tqi  = (float*)alloc((size_t)BB*HH*4);
  float* tpr  = (float*)alloc((size_t)BB*HH*4);
  float* tqr  = (float*)alloc((size_t)BB*HH*4);
  float* pbuf = (float*)alloc((size_t)5*BB*HH*4);
  u16*   zb0  = (u16*)  alloc((size_t)BB*HH*2);
  u16*   zb1  = (u16*)  alloc((size_t)BB*HH*2);
  u16*   zT0  = (u16*)  alloc((size_t)HH*BB*2);
  u16*   zT1  = (u16*)  alloc((size_t)HH*BB*2);
  u16*   tpiT = (u16*)  alloc((size_t)II*BB*2);
  u16*   xbT  = (u16*)  alloc((size_t)II*BB*2);
  u16*   tqiT = (u16*)  alloc((size_t)HH*BB*2);
  u16*   tprT = (u16*)  alloc((size_t)HH*BB*2);
  u16*   tqrT = (u16*)  alloc((size_t)HH*BB*2);
  u16* zb[2] = {zb0, zb1};
  u16* zT[2] = {zT0, zT1};

  hipMemsetAsync(v,    0, (size_t)BB*HH*4, stream);
  hipMemsetAsync(iS,   0, (size_t)BB*HH*4, stream);
  hipMemsetAsync(sc,   0, (size_t)BB*HH*4, stream);
  hipMemsetAsync(tpi,  0, (size_t)BB*II*4, stream);
  hipMemsetAsync(tqi,  0, (size_t)BB*HH*4, stream);
  hipMemsetAsync(tpr,  0, (size_t)BB*HH*4, stream);
  hipMemsetAsync(tqr,  0, (size_t)BB*HH*4, stream);
  hipMemsetAsync(zb0,  0, (size_t)BB*HH*2, stream);
  hipMemsetAsync(zb1,  0, (size_t)BB*HH*2, stream);
  hipMemsetAsync(zT0,  0, (size_t)HH*BB*2, stream);
  hipMemsetAsync(zT1,  0, (size_t)HH*BB*2, stream);
  hipMemsetAsync(o_total, 0, 4, stream);
  hipMemsetAsync(o_sc, 0, (size_t)LL*HH*4, stream);

  cast_w<<<1024, 256, 0, stream>>>((const f32x4*)w_in0,  (f32x4*)o_win,  (u16x4*)wib, (long long)HH*II/4);
  cast_w<<<2048, 256, 0, stream>>>((const f32x4*)w_rec0, (f32x4*)o_wrec, (u16x4*)wrb, (long long)HH*HH/4);
  cast_x<<<2048, 256, 0, stream>>>((const f32x4*)x, (u16x4*)xb, (long long)TSTEPS*BB*II/4);

  for (int t = 0; t < TSTEPS; ++t){
    int wi = t & 1, ri = wi ^ 1;
    const u16* xbt = xb + (size_t)t*BB*II;

    // in_cur partials: 5 planes of K=1024
    gemm_fwd<<<dim3(HH/64, BB/64, 5), 256, 0, stream>>>(xbt, wib, zb[ri], wrb, pbuf);

    step_state<<<dim3(HH/64, BB/16), 256, 0, stream>>>(
        pbuf, v, iS, sc, tqi, tpr, tqr,
        zb[ri], zb[wi], zT[wi], tqiT, tprT, tqrT);

    step_tpi<<<dim3(II/64, BB/16), 256, 0, stream>>>(xbt, tpi, tpiT, xbT);

    // w_in += 0.01 * z_new^T tp_i - 1e-4 * tq_i^T pre   (coeffs folded into bf16)
    gemm_upd<64,64,32,32><<<dim3(II/64, HH/64), 256, 0, stream>>>(
        zT[wi], tpiT, tqiT, xbT, o_win, wib, II);

    // w_rec += 0.01 * z_new^T tp_r - 1e-4 * tq_r^T z_old
    gemm_upd<128,128,64,64><<<dim3(HH/128, HH/128), 256, 0, stream>>>(
        zT[wi], tprT, tqrT, zT[ri], o_wrec, wrb, HH);
  }

  fin_logits  <<<BB, 256, 0, stream>>>(sc, o_logits, o_total);
  fin_spikecnt<<<HH/256, 256, 0, stream>>>(sc, label, o_sc);
  fin_labelcnt<<<1, 256, 0, stream>>>(label, o_lc);
}